// Round 3
// baseline (224.263 us; speedup 1.0000x reference)
//
#include <hip/hip_runtime.h>

typedef unsigned short ushort_t;
typedef __attribute__((ext_vector_type(8))) short short8;
typedef __attribute__((ext_vector_type(4))) float floatx4;

#define G_   129
#define F_   96
#define O_   96
#define T_   512
#define KD   288    // K*F, kd = kk*96 + f
#define LDB  296    // Wl padded row stride (288 + 8)
#define SROW 40     // x-slab row stride in ushorts (80 B) -> bank-conflict-free
#define SLAB (36 * SROW)   // per-wave slab: 36 rows (34 used) = 2880 B

// f32 -> bf16 RNE (finite inputs)
__device__ __forceinline__ unsigned f2bf(float f) {
    unsigned u = __builtin_bit_cast(unsigned, f);
    u += 0x7FFFu + ((u >> 16) & 1u);
    return u >> 16;
}
__device__ __forceinline__ unsigned pk2(float a, float b) {
    return f2bf(a) | (f2bf(b) << 16);
}

// One block = one group g x TWO 256-row m-tiles (barrier-free tile loop: x slabs
// are per-wave private). Weights staged once per block (amortized 2x), blocks of
// a group colocated on one XCD (xcd = g%8) so w comes from that XCD's L2.
// x pipeline is 3-deep (whole tile in flight); tile1's loads issue during tile0's
// last compute and stay outstanding across tile0's epilogue stores.
__global__ __launch_bounds__(512, 4) void conv_mfma(
    const float* __restrict__ x, const float* __restrict__ w,
    const float* __restrict__ bias, float* __restrict__ out)
{
    __shared__ __align__(16) ushort_t Wl[O_ * LDB];   // 56,832 B
    __shared__ __align__(16) ushort_t Xs[8 * SLAB];   // 23,040 B

    // XCD-colocating decode: bid -> (g, mt). xcd = bid&7; same-g blocks share xcd.
    const int bid = blockIdx.x;
    const int c   = bid & 7;
    const int s   = bid >> 3;          // slot on this xcd, 0..67
    const int g   = c + ((s >> 2) << 3);
    if (g >= G_) return;               // uniform per block; before any barrier
    const int mt  = s & 3;             // 4 mt-slots x 2 tiles = 8 m-tiles
    const int m0base = mt * 512;       // tiles: m0base, m0base+256 (same b)

    const int tid  = threadIdx.x;
    const int wave = tid >> 6;
    const int lane = tid & 63;
    const int ln   = lane & 15;
    const int q    = lane >> 4;

    // Tile-invariant staging constants: 5 tasks/lane; task -> (row, seg).
    int  laddr[5], rowv[5], segv[5];
    bool wr[5];
    #pragma unroll
    for (int i = 0; i < 5; ++i) {
        int task = i * 64 + lane;
        rowv[i] = task >> 3;            // 0..39
        segv[i] = task & 7;             // 8 segs x 4 floats
        wr[i]   = rowv[i] < 34;
        laddr[i] = wave * SLAB + rowv[i] * SROW + segv[i] * 4;
    }

    const float* tp[5];
    bool vld[5];
    auto computeTP = [&](int m0r) {     // per-tile pointers + validity
        int b  = m0r >> 9;
        int tb = m0r & 511;
        #pragma unroll
        for (int i = 0; i < 5; ++i) {
            int tl = tb + rowv[i] - 1;
            vld[i] = wr[i] && ((unsigned)tl < (unsigned)T_);
            int tc = tl < 0 ? 0 : (tl > T_ - 1 ? T_ - 1 : tl);
            tp[i] = x + ((size_t)((b * T_ + tc) * G_ + g) * F_ + segv[i] * 4);
        }
    };

    auto issueX = [&](int fb, floatx4* v) {
        #pragma unroll
        for (int i = 0; i < 5; ++i)
            v[i] = *(const floatx4*)(tp[i] + fb * 32);
    };
    auto writeX = [&](const floatx4* v) {
        #pragma unroll
        for (int i = 0; i < 5; ++i) {
            if (wr[i]) {
                unsigned lo = pk2(v[i][0], v[i][1]);
                unsigned hi = pk2(v[i][2], v[i][3]);
                if (!vld[i]) { lo = 0u; hi = 0u; }
                uint2 d; d.x = lo; d.y = hi;
                *(uint2*)&Xs[laddr[i]] = d;
            }
        }
    };

    floatx4 vA[5], vB[5], vC[5];
    computeTP(m0base + wave * 32);
    issueX(0, vA); issueX(1, vB); issueX(2, vC);   // whole tile0 in flight

    // Fused weight stage: 12 consecutive f32 of w[g][o] per task; floats j=0..11
    // are (f,kk)=(4u+j/3, j%3); repack to three uint2 at Wl[o*LDB + kk*96 + 4u].
    {
        const float* wg = w + (size_t)g * (O_ * KD);
        #pragma unroll
        for (int i = 0; i < 5; ++i) {
            int task = i * 512 + tid;
            if (task < 2304) {
                int o = task / 24;
                int u = task - o * 24;
                const float* p = wg + o * KD + u * 12;
                float4 A = *(const float4*)(p);
                float4 B = *(const float4*)(p + 4);
                float4 C = *(const float4*)(p + 8);
                int base = o * LDB + u * 4;
                uint2 d0, d1, d2;
                d0.x = pk2(A.x, A.w);  d0.y = pk2(B.z, C.y);   // kk=0
                d1.x = pk2(A.y, B.x);  d1.y = pk2(B.w, C.z);   // kk=1
                d2.x = pk2(A.z, B.y);  d2.y = pk2(C.x, C.w);   // kk=2
                *(uint2*)&Wl[base]       = d0;
                *(uint2*)&Wl[base +  96] = d1;
                *(uint2*)&Wl[base + 192] = d2;
            }
        }
    }

    float bv[6];
    #pragma unroll
    for (int nt = 0; nt < 6; ++nt) bv[nt] = bias[g * O_ + nt * 16 + ln];

    __syncthreads();   // the only barrier

    floatx4 acc[2][6];
    auto zeroAcc = [&]() {
        #pragma unroll
        for (int s2 = 0; s2 < 2; ++s2)
            #pragma unroll
            for (int nt = 0; nt < 6; ++nt)
                acc[s2][nt] = (floatx4){0.f, 0.f, 0.f, 0.f};
    };

    auto compute = [&](int fb) {
        #pragma unroll
        for (int kk = 0; kk < 3; ++kk) {
            const short8 a0 = *(const short8*)&Xs[wave * SLAB + (ln + kk) * SROW + q * 8];
            const short8 a1 = *(const short8*)&Xs[wave * SLAB + (16 + ln + kk) * SROW + q * 8];
            const int c32 = (kk * 3 + fb) * 32;
            #pragma unroll
            for (int nt = 0; nt < 6; ++nt) {
                const short8 bbv = *(const short8*)&Wl[(nt * 16 + ln) * LDB + c32 + q * 8];
                acc[0][nt] = __builtin_amdgcn_mfma_f32_16x16x32_bf16(a0, bbv, acc[0][nt], 0, 0, 0);
                acc[1][nt] = __builtin_amdgcn_mfma_f32_16x16x32_bf16(a1, bbv, acc[1][nt], 0, 0, 0);
            }
        }
    };

    auto epilogue = [&](int m0t) {
        #pragma unroll
        for (int s2 = 0; s2 < 2; ++s2) {
            int mbase = m0t + wave * 32 + s2 * 16 + q * 4;
            #pragma unroll
            for (int nt = 0; nt < 6; ++nt) {
                int o = nt * 16 + ln;
                #pragma unroll
                for (int r = 0; r < 4; ++r) {
                    int m = mbase + r;
                    out[(size_t)(m * G_ + g) * O_ + o] = acc[s2][nt][r] + bv[nt];
                }
            }
        }
    };

    zeroAcc();

    // ---- tile 0 ----
    writeX(vA); compute(0);
    writeX(vB); compute(1);
    writeX(vC);                       // consumes tile0's vld (before recompute!)
    computeTP(m0base + 256 + wave * 32);   // VALU, overlaps with compute(2)
    issueX(0, vA); issueX(1, vB); issueX(2, vC);   // tile1 loads in flight
    compute(2);
    epilogue(m0base);                 // 48 stores overlap tile1's loads
    zeroAcc();

    // ---- tile 1 ----
    writeX(vA); compute(0);
    writeX(vB); compute(1);
    writeX(vC); compute(2);
    epilogue(m0base + 256);
}

extern "C" void kernel_launch(void* const* d_in, const int* in_sizes, int n_in,
                              void* d_out, int out_size, void* d_ws, size_t ws_size,
                              hipStream_t stream) {
    const float* x    = (const float*)d_in[0];
    const float* w    = (const float*)d_in[1];
    const float* bias = (const float*)d_in[2];
    float* out = (float*)d_out;
    conv_mfma<<<dim3(544), dim3(512), 0, stream>>>(x, w, bias, out);
}